// Round 15
// baseline (9059.303 us; speedup 1.0000x reference)
//
#include <hip/hip_runtime.h>

// Problem constants: N=1024, K=32, F=8192, E=64, H1=128, H2=64, T=3

typedef float f32x4 __attribute__((ext_vector_type(4)));
typedef float f32x2 __attribute__((ext_vector_type(2)));
typedef short bf16x8 __attribute__((ext_vector_type(8)));

__device__ __forceinline__ unsigned short bf16_rne(float x) {
  unsigned u = __builtin_bit_cast(unsigned, x);
  unsigned r = (u + 0x7FFFu + ((u >> 16) & 1u)) >> 16;
  return (unsigned short)r;
}
__device__ __forceinline__ float bf16_f(unsigned short h) {
  return __builtin_bit_cast(float, ((unsigned)h) << 16);
}
__device__ __forceinline__ void split3(float x, unsigned short& h, unsigned short& m,
                                       unsigned short& l) {
  h = bf16_rne(x); float r  = x - bf16_f(h);
  m = bf16_rne(r); float r2 = r - bf16_f(m);
  l = bf16_rne(r2);
}
// pair split via v_cvt_pk_bf16_f32 (verified on gfx950: dst = {lo=cvt(src0),
// hi=cvt(src1)}; split-3 residual planes absorb any tie-rounding delta)
__device__ __forceinline__ void split3_pk(float x, float y,
                                          unsigned& ph, unsigned& pm, unsigned& pl) {
  asm("v_cvt_pk_bf16_f32 %0, %1, %2" : "=v"(ph) : "v"(x), "v"(y));
  float xh = __builtin_bit_cast(float, ph << 16);
  float yh = __builtin_bit_cast(float, ph & 0xFFFF0000u);
  float rx = x - xh, ry = y - yh;
  asm("v_cvt_pk_bf16_f32 %0, %1, %2" : "=v"(pm) : "v"(rx), "v"(ry));
  float xm = __builtin_bit_cast(float, pm << 16);
  float ym = __builtin_bit_cast(float, pm & 0xFFFF0000u);
  float r2x = rx - xm, r2y = ry - ym;
  asm("v_cvt_pk_bf16_f32 %0, %1, %2" : "=v"(pl) : "v"(r2x), "v"(r2y));
}

// xor-16 partner add via ds_swizzle (ISA-doc-verified BitMode pattern:
// offset = (xor<<10)|(or<<5)|and = 0x401F -> lane ^= 16 within 32-lane group,
// bit5 preserved -> lane^16 for all 64 lanes). Float add is commutative so
// both partners hold the bit-identical pair sum.
__device__ __forceinline__ float swz16_add(float p) {
  int o = __builtin_amdgcn_ds_swizzle(__builtin_bit_cast(int, p), 0x401F);
  return p + __builtin_bit_cast(float, o);
}

// Raw workgroup barrier waiting only on LDS (lgkmcnt), not in-flight global
// stores; one full __syncthreads() per node provides store visibility.
__device__ __forceinline__ void bar_lgkm() {
  __builtin_amdgcn_sched_barrier(0);
  asm volatile("s_waitcnt lgkmcnt(0)" ::: "memory");
  __builtin_amdgcn_s_barrier();
  asm volatile("" ::: "memory");
  __builtin_amdgcn_sched_barrier(0);
}

// ---------------------------------------------------------------------------
// K1: G0 = X @ W_emb (f64 accumulation), feat0 = relu(G0 + b_emb), out=feat0
// ---------------------------------------------------------------------------
__global__ __launch_bounds__(256) void k_embed(
    const float* __restrict__ X, const float* __restrict__ W_emb,
    const float* __restrict__ b_emb,
    float* __restrict__ G0, float* __restrict__ feat0, float* __restrict__ out)
{
  const int t = threadIdx.x;
  const int j = t & 63;
  const int node = (blockIdx.x << 2) + (t >> 6);
  const float* __restrict__ xr = X + (size_t)node * 8192;
  const float* __restrict__ wp = W_emb + j;
  double a0 = 0.0, a1 = 0.0, a2 = 0.0, a3 = 0.0;
  for (int f = 0; f < 8192; f += 4) {
    float x0 = xr[f + 0], x1 = xr[f + 1], x2 = xr[f + 2], x3 = xr[f + 3];
    a0 = fma((double)x0, (double)wp[(f + 0) << 6], a0);
    a1 = fma((double)x1, (double)wp[(f + 1) << 6], a1);
    a2 = fma((double)x2, (double)wp[(f + 2) << 6], a2);
    a3 = fma((double)x3, (double)wp[(f + 3) << 6], a3);
  }
  float g = (float)((a0 + a1) + (a2 + a3));
  const int o = node * 64 + j;
  G0[o] = g;
  float f0 = fmaxf(g + b_emb[j], 0.0f);
  feat0[o] = f0;
  out[o] = f0;
}

// ---------------------------------------------------------------------------
// K2: Y0 = feat0 @ W1b (W1 rows 64..127); Y = Y0 working copy
// ---------------------------------------------------------------------------
__global__ __launch_bounds__(128) void k_y0(
    const float* __restrict__ feat0, const float* __restrict__ W1,
    float* __restrict__ Y0, float* __restrict__ Y)
{
  const int c = threadIdx.x;
  const int i = blockIdx.x;
  const float* __restrict__ fr = feat0 + i * 64;
  float acc = 0.0f;
  #pragma unroll 8
  for (int e = 0; e < 64; ++e)
    acc = fmaf(fr[e], W1[(64 + e) * 128 + c], acc);
  Y0[i * 128 + c] = acc;
  Y[i * 128 + c] = acc;
}

// ---------------------------------------------------------------------------
// K3: serial chain, 512 threads / 8 waves. MFMA B2.
// Round-15: (a) B2 accumulators split into two half-depth chains (kc 0-1 /
// kc 2-3) merged by one vector add -> dependent-MFMA chain 24 -> 12 deep
// (reassociates lk by ~1e-7; prior evidence shows decision gaps >> this);
// (b) epilogue xor-16 fold via ds_swizzle (bit-identical association) ->
// P4 trip-1 = 2 b128/lane, trip-3 = 4 b128 broadcast (half the LDS traffic).
// ---------------------------------------------------------------------------
__global__ __launch_bounds__(512, 2) void k_serial(
    const int* __restrict__ neighbors,
    const float* __restrict__ W1, const float* __restrict__ b1,
    const float* __restrict__ W2, const float* __restrict__ b2,
    const float* __restrict__ W_lk, const float* __restrict__ b_lk,
    const float* __restrict__ W_act, const float* __restrict__ b_act,
    const float* __restrict__ b_emb,
    const float* __restrict__ G0, const float* __restrict__ feat0,
    const float* __restrict__ Y0, float* __restrict__ Y,
    float* __restrict__ feature)   // == d_out
{
  __shared__ __align__(16) float W1T[128 * 130];            // 66.6 KB full W1^T
  __shared__ __align__(16) unsigned short Ash[48 * 128];    // 12 KB h1 hi plane
  __shared__ __align__(16) unsigned short Asm[48 * 128];    // 12 KB h1 mid plane
  __shared__ __align__(16) unsigned short Asl[48 * 128];    // 12 KB h1 lo plane
  __shared__ __align__(16) float Yl[32][128];               // 16 KB
  __shared__ __align__(16) float Y0l[32][128];              // 16 KB
  __shared__ __align__(16) float G0l[32][64];               // 8 KB
  __shared__ __align__(16) float a1s[128];
  __shared__ __align__(16) float fis[64];
  __shared__ __align__(16) float b1s[128];
  __shared__ __align__(16) float lkraw2[64 * 12];           // 3 KB [row][c8] pad12
  __shared__ __align__(16) float p01raw2[32 * 20];          // 2.5 KB [row][c8*2] pad20
  __shared__ __align__(16) unsigned keybuf[64];
  __shared__ int idxs[32];
  __shared__ int s_u, s_upd, s_utc;
  __shared__ unsigned s_mu, s_mi;

  const int t = threadIdx.x;
  const int lane = t & 63;
  const int wave = t >> 6;
  const int l15 = lane & 15;
  const int lg = lane >> 4;            // 0..3
  const int mt = wave & 3;             // W2-col tile
  const int m0 = mt << 4;
  const int c8 = (mt << 1) + (lg >> 1);  // folded-partial column id (0..7)

  unsigned* const uAsh = (unsigned*)Ash;
  unsigned* const uAsm = (unsigned*)Asm;
  unsigned* const uAsl = (unsigned*)Asl;

  // ---- one-time staging: full transposed W1 (coalesced global reads) ----
  for (int idx = t; idx < 16384; idx += 512) {
    int e = idx >> 7, c = idx & 127;     // consecutive lanes -> consecutive c
    W1T[c * 130 + e] = W1[e * 128 + c];
  }
  if (t < 128) b1s[t] = b1[t];
  for (int idx = 33 * 64 + t; idx < 48 * 64; idx += 512) {  // zero pad rows
    uAsh[idx] = 0u; uAsm[idx] = 0u; uAsl[idx] = 0u;
  }
  const float blkv = b_lk[0];
  const float ba0 = b_act[0];
  const float ba1 = b_act[1];
  const float bembr = b_emb[lane];
  // W2^T A-frags split-3 in VGPRs: col = m0+l15, k = 32kc + 8lg + e
  bf16x8 wh[4], wm[4], wl[4];
  #pragma unroll
  for (int kc = 0; kc < 4; ++kc) {
    bf16x8 vh, vm_, vl;
    #pragma unroll
    for (int e = 0; e < 8; ++e) {
      int k = (kc << 5) + (lg << 3) + e;
      float x = W2[k * 64 + m0 + l15];
      unsigned short sh, sm, sl;
      split3(x, sh, sm, sl);
      vh[e] = (short)sh; vm_[e] = (short)sm; vl[e] = (short)sl;
    }
    wh[kc] = vh; wm[kc] = vm_; wl[kc] = vl;
  }
  // hoisted epilogue constants
  const f32x4 c0init = *(const f32x4*)&b2[m0 + (lg << 2)];
  const f32x4 wl4 = *(const f32x4*)&W_lk[m0 + (lg << 2)];
  f32x4 wa0v, wa1v;
  #pragma unroll
  for (int r = 0; r < 4; ++r) {
    f32x2 w2a = *(const f32x2*)&W_act[(m0 + (lg << 2) + r) << 1];
    wa0v[r] = w2a[0]; wa1v[r] = w2a[1];
  }
  // hoisted B1 constants
  int kk[4]; unsigned wb[4]; const float2* ylp[4];
  #pragma unroll
  for (int n = 0; n < 4; ++n) {
    kk[n] = wave + (n << 3);
    wb[n] = (unsigned)((kk[n] << 6) + (lane ^ ((kk[n] & 7) << 2)));
    ylp[n] = (const float2*)&Yl[kk[n]][lane << 1];
  }
  const unsigned wb32 = 2048u + (unsigned)lane;   // row 32, swz=0
  // hoisted B2 read offsets (ushort units)
  const int ntA = (wave < 4) ? 0 : 1;
  const int rowA = (ntA << 4) + l15;
  const int rowB = 32 + l15;                       // only waves 0-3
  int aoA[4], aoB[4];
  #pragma unroll
  for (int kc = 0; kc < 4; ++kc) {
    aoA[kc] = (rowA << 7) + ((((kc << 2) + lg) ^ (rowA & 7)) << 3);
    aoB[kc] = (rowB << 7) + ((((kc << 2) + lg) ^ (rowB & 7)) << 3);
  }
  const float2* const a1p = (const float2*)&a1s[lane << 1];
  // wave-0 register state
  unsigned vm = 0xFFFFFFFFu; float cntf = 0.f; int done = 0;
  int ridx = 0; float gisr = 0.f, sumgr = 0.f;
  // next-node prefetch registers (neighbors / G0 are read-only)
  int vA0 = neighbors[t >> 5];
  int vA1 = neighbors[16 + (t >> 5)];
  int vB  = neighbors[t >> 4];
  int vI  = (t < 32) ? neighbors[t] : 0;
  float gn = (wave == 0) ? G0[lane] : 0.f;

  for (int i = 0; i < 1024; ++i) {
    // ---- full drain once per node: prior node's feature/Y stores must be
    //      visible to this node's phase0 loads ----
    __syncthreads();
    const float gcur = gn;
    // ---- phase0: per-node prefetch into LDS (v-indices already in regs) ----
    {
      const int c4 = (t & 31) << 2;
      *(float4*)&Yl [t >> 5][c4]        = *(const float4*)&Y [vA0 * 128 + c4];
      *(float4*)&Y0l[t >> 5][c4]        = *(const float4*)&Y0[vA0 * 128 + c4];
      *(float4*)&Yl [16 + (t >> 5)][c4] = *(const float4*)&Y [vA1 * 128 + c4];
      *(float4*)&Y0l[16 + (t >> 5)][c4] = *(const float4*)&Y0[vA1 * 128 + c4];
    }
    {
      int k = t >> 4;
      int c4 = (t & 15) << 2;
      *(float4*)&G0l[k][c4] = *(const float4*)&G0[vB * 64 + c4];
    }
    if (t < 64) fis[t] = feature[(i << 6) + t];
    if (t < 32) idxs[t] = vI;
    // issue next node's register prefetch (independent, read-only)
    {
      int j = (i + 1) & 1023;
      const int* __restrict__ nb = neighbors + (j << 5);
      vA0 = nb[t >> 5];
      vA1 = nb[16 + (t >> 5)];
      vB  = nb[t >> 4];
      if (t < 32) vI = nb[t];
      if (wave == 0) gn = G0[(j << 6) + lane];
    }
    bar_lgkm();
    // ---- a1 = fi @ W1a + b1 (W1T b64 reads; chain bit-identical) ----
    if (t < 128) {
      float aa0 = b1s[t], aa1 = 0.0f;
      const float* w1r = &W1T[t * 130];
      #pragma unroll 8
      for (int e = 0; e < 64; e += 2) {
        f32x2 wv = *(const f32x2*)&w1r[e];
        aa0 = fmaf(fis[e],     wv[0], aa0);
        aa1 = fmaf(fis[e + 1], wv[1], aa1);
      }
      a1s[t] = aa0 + aa1;
    }
    int vn[4];
    #pragma unroll
    for (int n = 0; n < 4; ++n) vn[n] = idxs[kk[n]];
    if (wave == 0) {
      ridx = idxs[lane & 31];
      gisr = gcur;
      sumgr = 0.f; vm = 0xFFFFFFFFu; cntf = 0.f; done = 0;
    }
    bar_lgkm();

    for (int st = 0; st < 3; ++st) {
      // ---- B1: 4 rows/wave (+row 32 by wave 4); cvt_pk split-3 ----
      {
        float2 av = *a1p;
        #pragma unroll
        for (int n = 0; n < 4; ++n) {
          float hx = av.x, hy = av.y;
          if (vn[n] > 0) {                         // wave-uniform branch
            float2 yv = *ylp[n];
            hx += yv.x; hy += yv.y;
          }
          hx = fmaxf(hx, 0.f); hy = fmaxf(hy, 0.f);
          unsigned ph, pm, pl;
          split3_pk(hx, hy, ph, pm, pl);
          uAsh[wb[n]] = ph; uAsm[wb[n]] = pm; uAsl[wb[n]] = pl;
        }
        if (wave == 4) {
          float hx = fmaxf(av.x, 0.f), hy = fmaxf(av.y, 0.f);
          unsigned ph, pm, pl;
          split3_pk(hx, hy, ph, pm, pl);
          uAsh[wb32] = ph; uAsm[wb32] = pm; uAsl[wb32] = pl;
        }
      }
      bar_lgkm();
      // ---- B2: MFMA tiles, split accumulator chains (kc01 / kc23) ----
      {
        f32x4 cAa = c0init, cAb = {0.f, 0.f, 0.f, 0.f};
        f32x4 cBa = c0init, cBb = {0.f, 0.f, 0.f, 0.f};
        const bool twoT = (wave < 4);
        #pragma unroll
        for (int kc = 0; kc < 4; ++kc) {
          bf16x8 ahA = *(const bf16x8*)&Ash[aoA[kc]];
          bf16x8 amA = *(const bf16x8*)&Asm[aoA[kc]];
          bf16x8 alA = *(const bf16x8*)&Asl[aoA[kc]];
          f32x4 c0 = (kc < 2) ? cAa : cAb;
          c0 = __builtin_amdgcn_mfma_f32_16x16x32_bf16(wh[kc], ahA, c0, 0, 0, 0);
          c0 = __builtin_amdgcn_mfma_f32_16x16x32_bf16(wh[kc], amA, c0, 0, 0, 0);
          c0 = __builtin_amdgcn_mfma_f32_16x16x32_bf16(wm[kc], ahA, c0, 0, 0, 0);
          c0 = __builtin_amdgcn_mfma_f32_16x16x32_bf16(wh[kc], alA, c0, 0, 0, 0);
          c0 = __builtin_amdgcn_mfma_f32_16x16x32_bf16(wl[kc], ahA, c0, 0, 0, 0);
          c0 = __builtin_amdgcn_mfma_f32_16x16x32_bf16(wm[kc], amA, c0, 0, 0, 0);
          if (kc < 2) cAa = c0; else cAb = c0;
          if (twoT) {
            bf16x8 ahB = *(const bf16x8*)&Ash[aoB[kc]];
            bf16x8 amB = *(const bf16x8*)&Asm[aoB[kc]];
            bf16x8 alB = *(const bf16x8*)&Asl[aoB[kc]];
            f32x4 c1 = (kc < 2) ? cBa : cBb;
            c1 = __builtin_amdgcn_mfma_f32_16x16x32_bf16(wh[kc], ahB, c1, 0, 0, 0);
            c1 = __builtin_amdgcn_mfma_f32_16x16x32_bf16(wh[kc], amB, c1, 0, 0, 0);
            c1 = __builtin_amdgcn_mfma_f32_16x16x32_bf16(wm[kc], ahB, c1, 0, 0, 0);
            c1 = __builtin_amdgcn_mfma_f32_16x16x32_bf16(wh[kc], alB, c1, 0, 0, 0);
            c1 = __builtin_amdgcn_mfma_f32_16x16x32_bf16(wl[kc], ahB, c1, 0, 0, 0);
            c1 = __builtin_amdgcn_mfma_f32_16x16x32_bf16(wm[kc], amB, c1, 0, 0, 0);
            if (kc < 2) cBa = c1; else cBb = c1;
          }
        }
        const f32x4 cA = cAa + cAb;
        // epilogue A: per-lg partials, fold lg-pairs via ds_swizzle xor-16
        {
          float pl = 0.f, q0 = 0.f, q1 = 0.f;
          #pragma unroll
          for (int r = 0; r < 4; ++r) {
            float v = fmaxf(cA[r], 0.f);
            pl = fmaf(v, wl4[r], pl);
            q0 = fmaf(v, wa0v[r], q0);
            q1 = fmaf(v, wa1v[r], q1);
          }
          pl = swz16_add(pl);
          q0 = swz16_add(q0);
          q1 = swz16_add(q1);
          if ((lg & 1) == 0) {
            lkraw2[rowA * 12 + c8] = pl;
            *(f32x2*)&p01raw2[rowA * 20 + (c8 << 1)] = (f32x2){q0, q1};
          }
        }
        if (twoT) {   // row 32 never feeds the action head: lk partial only
          const f32x4 cB = cBa + cBb;
          float pl = 0.f;
          #pragma unroll
          for (int r = 0; r < 4; ++r) {
            float v = fmaxf(cB[r], 0.f);
            pl = fmaf(v, wl4[r], pl);
          }
          pl = swz16_add(pl);
          if ((lg & 1) == 0) lkraw2[rowB * 12 + c8] = pl;
        }
      }
      bar_lgkm();
      // ---- P4+D (wave 0): assemble lk (bit-identical nesting), LDS-key
      //      argmax, action head, state update ----
      if (wave == 0) {
        const f32x4* lr = (const f32x4*)&lkraw2[lane * 12];
        f32x4 va = lr[0], vb = lr[1];
        float t0 = va[0] + va[1], t1 = va[2] + va[3];
        float t2 = vb[0] + vb[1], t3 = vb[2] + vb[3];
        float lkv = ((t0 + t1) + (t2 + t3)) + blkv;
        unsigned b = __builtin_bit_cast(unsigned, lkv);
        int sb = (int)b >> 31;
        unsigned mono = b ^ (0x80000000u | (unsigned)sb);
        bool valid = (lane == 32) || ((lane < 32) && ((vm >> lane) & 1u));
        unsigned key = valid ? mono : 0u;
        keybuf[lane] = key;
        asm volatile("s_waitcnt lgkmcnt(0)" ::: "memory");
        __builtin_amdgcn_sched_barrier(0);
        const uint4* kb = (const uint4*)keybuf;
        unsigned mx = 0u;
        #pragma unroll
        for (int c = 0; c < 16; ++c) {
          uint4 kv = kb[c];
          unsigned m01 = kv.x > kv.y ? kv.x : kv.y;
          unsigned m23 = kv.z > kv.w ? kv.z : kv.w;
          unsigned mm = m01 > m23 ? m01 : m23;
          mx = mx > mm ? mx : mm;
        }
        unsigned long long am = __ballot(valid && (key == mx));
        const int ut = (int)(__ffsll(am) - 1);
        const int utc = ut < 31 ? ut : 31;
        // action head: 4 b128 broadcast reads of folded partials at utc
        const f32x4* pr = (const f32x4*)&p01raw2[utc * 20];
        f32x4 qa = pr[0], qb = pr[1], qc = pr[2], qd = pr[3];
        float T00 = qa[0] + qa[2], T01 = qa[1] + qa[3];   // mt0
        float T10 = qb[0] + qb[2], T11 = qb[1] + qb[3];   // mt1
        float T20 = qc[0] + qc[2], T21 = qc[1] + qc[3];   // mt2
        float T30 = qd[0] + qd[2], T31 = qd[1] + qd[3];   // mt3
        float d0 = ((T00 + T10) + (T20 + T30)) + ba0;
        float d1 = ((T01 + T11) + (T21 + T31)) + ba1;
        const int at1 = (d1 > d0) ? 1 : 0;
        const int newdone = done | (ut == 32);
        const int upd = newdone ? 0 : 1;
        done = newdone;
        const float take = at1 ? 1.0f : 0.0f;
        const float denom = cntf + take + 1.0f;
        const int u = __builtin_amdgcn_readlane(ridx, utc);
        unsigned long long bu = __ballot(lane < 32 && ridx == u);
        unsigned long long bi = __ballot(lane < 32 && ridx == i);
        if (lane == 0) {
          s_u = u; s_upd = upd; s_utc = utc;
          s_mu = (unsigned)bu; s_mi = (unsigned)bi;
        }
        if (upd) {
          vm &= ~(1u << utc);
          cntf += take;
          const float gu = G0l[utc][lane];
          const float ns = sumgr + take * gu;
          const float hv = (ns + gisr) / denom;
          const float nfi = fmaxf(hv + bembr, 0.0f);
          sumgr = ns;
          const float f0u = fmaxf(gu + bembr, 0.0f);   // == feat0[u] bit-exact
          feature[(i << 6) + lane] = nfi;              // feature[u] wins if u==i
          feature[(u << 6) + lane] = f0u;
          fis[lane] = (u == i) ? f0u : nfi;
        }
      }
      bar_lgkm();
      if (!s_upd) break;
      // ---- E: waves 0-1 -> Y rows + Yl patches; waves 2-3 -> a1 ----
      if (wave < 4) {
        const int u = s_u;
        const int c = t & 127;
        const float* w1r = &W1T[c * 130];
        if (wave < 2) {
          const float yu = Y0l[s_utc][c];              // LDS (was global Y0[u])
          f32x2 acc = {0.f, 0.f};
          #pragma unroll 8
          for (int e = 0; e < 64; e += 2) {
            f32x2 fv = *(const f32x2*)&fis[e];
            f32x2 wv = *(const f32x2*)&w1r[64 + e];
            acc = __builtin_elementwise_fma(fv, wv, acc);
          }
          const float yi = acc[0] + acc[1];
          Y[i * 128 + c] = yi;                         // Y[u] wins if u==i
          Y[u * 128 + c] = yu;
          const unsigned mu = s_mu;
          for (unsigned m = mu; m; m &= m - 1) {
            int k = __ffs(m) - 1;
            Yl[k][c] = yu;
          }
          for (unsigned m = s_mi & ~mu; m; m &= m - 1) {
            int k = __ffs(m) - 1;
            Yl[k][c] = yi;
          }
        } else {
          f32x2 aa = {b1s[c], 0.f};
          #pragma unroll 8
          for (int e = 0; e < 64; e += 2) {
            f32x2 fv = *(const f32x2*)&fis[e];
            f32x2 wv = *(const f32x2*)&w1r[e];
            aa = __builtin_elementwise_fma(fv, wv, aa);
          }
          a1s[c] = aa[0] + aa[1];
        }
      }
      bar_lgkm();
    }
  }
}

// ---------------------------------------------------------------------------
extern "C" void kernel_launch(void* const* d_in, const int* in_sizes, int n_in,
                              void* d_out, int out_size, void* d_ws, size_t ws_size,
                              hipStream_t stream) {
  const float* X     = (const float*)d_in[0];
  const int*   nbr   = (const int*)  d_in[1];
  const float* W_emb = (const float*)d_in[2];
  const float* b_emb = (const float*)d_in[3];
  const float* W1    = (const float*)d_in[4];
  const float* b1    = (const float*)d_in[5];
  const float* W2    = (const float*)d_in[6];
  const float* b2    = (const float*)d_in[7];
  const float* W_lk  = (const float*)d_in[8];
  const float* b_lk  = (const float*)d_in[9];
  const float* W_act = (const float*)d_in[10];
  const float* b_act = (const float*)d_in[11];
  float* out = (float*)d_out;
  float* ws  = (float*)d_ws;
  float* G0    = ws;             // [1024*64]
  float* feat0 = ws + 65536;     // [1024*64]
  float* Y0    = ws + 131072;    // [1024*128]
  float* Y     = ws + 262144;    // [1024*128]

  hipLaunchKernelGGL(k_embed, dim3(256), dim3(256), 0, stream,
                     X, W_emb, b_emb, G0, feat0, out);
  hipLaunchKernelGGL(k_y0, dim3(1024), dim3(128), 0, stream,
                     feat0, W1, Y0, Y);
  hipLaunchKernelGGL(k_serial, dim3(1), dim3(512), 0, stream,
                     nbr, W1, b1, W2, b2, W_lk, b_lk, W_act, b_act, b_emb,
                     G0, feat0, Y0, Y, out);
}

// Round 16
// 8966.142 us; speedup vs baseline: 1.0104x; 1.0104x over previous
//
#include <hip/hip_runtime.h>

// Problem constants: N=1024, K=32, F=8192, E=64, H1=128, H2=64, T=3
// FINAL: round-14 structure (best measured: 8.97 ms) — MFMA B2 with split-3
// bf16 planes, W1T LDS, Y0l prefetch, next-node register prefetch, lgkm-only
// barriers. Round-15's chain-split + ds_swizzle fold reverted (regressive).

typedef float f32x4 __attribute__((ext_vector_type(4)));
typedef float f32x2 __attribute__((ext_vector_type(2)));
typedef short bf16x8 __attribute__((ext_vector_type(8)));

__device__ __forceinline__ unsigned short bf16_rne(float x) {
  unsigned u = __builtin_bit_cast(unsigned, x);
  unsigned r = (u + 0x7FFFu + ((u >> 16) & 1u)) >> 16;
  return (unsigned short)r;
}
__device__ __forceinline__ float bf16_f(unsigned short h) {
  return __builtin_bit_cast(float, ((unsigned)h) << 16);
}
__device__ __forceinline__ void split3(float x, unsigned short& h, unsigned short& m,
                                       unsigned short& l) {
  h = bf16_rne(x); float r  = x - bf16_f(h);
  m = bf16_rne(r); float r2 = r - bf16_f(m);
  l = bf16_rne(r2);
}
// pair split via v_cvt_pk_bf16_f32 (verified on gfx950: dst = {lo=cvt(src0),
// hi=cvt(src1)}; split-3 residual planes absorb any tie-rounding delta)
__device__ __forceinline__ void split3_pk(float x, float y,
                                          unsigned& ph, unsigned& pm, unsigned& pl) {
  asm("v_cvt_pk_bf16_f32 %0, %1, %2" : "=v"(ph) : "v"(x), "v"(y));
  float xh = __builtin_bit_cast(float, ph << 16);
  float yh = __builtin_bit_cast(float, ph & 0xFFFF0000u);
  float rx = x - xh, ry = y - yh;
  asm("v_cvt_pk_bf16_f32 %0, %1, %2" : "=v"(pm) : "v"(rx), "v"(ry));
  float xm = __builtin_bit_cast(float, pm << 16);
  float ym = __builtin_bit_cast(float, pm & 0xFFFF0000u);
  float r2x = rx - xm, r2y = ry - ym;
  asm("v_cvt_pk_bf16_f32 %0, %1, %2" : "=v"(pl) : "v"(r2x), "v"(r2y));
}

// Raw workgroup barrier waiting only on LDS (lgkmcnt), not in-flight global
// stores; one full __syncthreads() per node provides store visibility.
__device__ __forceinline__ void bar_lgkm() {
  __builtin_amdgcn_sched_barrier(0);
  asm volatile("s_waitcnt lgkmcnt(0)" ::: "memory");
  __builtin_amdgcn_s_barrier();
  asm volatile("" ::: "memory");
  __builtin_amdgcn_sched_barrier(0);
}

// ---------------------------------------------------------------------------
// K1: G0 = X @ W_emb (f64 accumulation), feat0 = relu(G0 + b_emb), out=feat0
// ---------------------------------------------------------------------------
__global__ __launch_bounds__(256) void k_embed(
    const float* __restrict__ X, const float* __restrict__ W_emb,
    const float* __restrict__ b_emb,
    float* __restrict__ G0, float* __restrict__ feat0, float* __restrict__ out)
{
  const int t = threadIdx.x;
  const int j = t & 63;
  const int node = (blockIdx.x << 2) + (t >> 6);
  const float* __restrict__ xr = X + (size_t)node * 8192;
  const float* __restrict__ wp = W_emb + j;
  double a0 = 0.0, a1 = 0.0, a2 = 0.0, a3 = 0.0;
  for (int f = 0; f < 8192; f += 4) {
    float x0 = xr[f + 0], x1 = xr[f + 1], x2 = xr[f + 2], x3 = xr[f + 3];
    a0 = fma((double)x0, (double)wp[(f + 0) << 6], a0);
    a1 = fma((double)x1, (double)wp[(f + 1) << 6], a1);
    a2 = fma((double)x2, (double)wp[(f + 2) << 6], a2);
    a3 = fma((double)x3, (double)wp[(f + 3) << 6], a3);
  }
  float g = (float)((a0 + a1) + (a2 + a3));
  const int o = node * 64 + j;
  G0[o] = g;
  float f0 = fmaxf(g + b_emb[j], 0.0f);
  feat0[o] = f0;
  out[o] = f0;
}

// ---------------------------------------------------------------------------
// K2: Y0 = feat0 @ W1b (W1 rows 64..127); Y = Y0 working copy
// ---------------------------------------------------------------------------
__global__ __launch_bounds__(128) void k_y0(
    const float* __restrict__ feat0, const float* __restrict__ W1,
    float* __restrict__ Y0, float* __restrict__ Y)
{
  const int c = threadIdx.x;
  const int i = blockIdx.x;
  const float* __restrict__ fr = feat0 + i * 64;
  float acc = 0.0f;
  #pragma unroll 8
  for (int e = 0; e < 64; ++e)
    acc = fmaf(fr[e], W1[(64 + e) * 128 + c], acc);
  Y0[i * 128 + c] = acc;
  Y[i * 128 + c] = acc;
}

// ---------------------------------------------------------------------------
// K3: serial chain, 512 threads / 8 waves. MFMA B2 (round-14 structure).
// ---------------------------------------------------------------------------
__global__ __launch_bounds__(512, 2) void k_serial(
    const int* __restrict__ neighbors,
    const float* __restrict__ W1, const float* __restrict__ b1,
    const float* __restrict__ W2, const float* __restrict__ b2,
    const float* __restrict__ W_lk, const float* __restrict__ b_lk,
    const float* __restrict__ W_act, const float* __restrict__ b_act,
    const float* __restrict__ b_emb,
    const float* __restrict__ G0, const float* __restrict__ feat0,
    const float* __restrict__ Y0, float* __restrict__ Y,
    float* __restrict__ feature)   // == d_out
{
  __shared__ __align__(16) float W1T[128 * 130];            // 66.6 KB full W1^T
  __shared__ __align__(16) unsigned short Ash[48 * 128];    // 12 KB h1 hi plane
  __shared__ __align__(16) unsigned short Asm[48 * 128];    // 12 KB h1 mid plane
  __shared__ __align__(16) unsigned short Asl[48 * 128];    // 12 KB h1 lo plane
  __shared__ __align__(16) float Yl[32][128];               // 16 KB
  __shared__ __align__(16) float Y0l[32][128];              // 16 KB
  __shared__ __align__(16) float G0l[32][64];               // 8 KB
  __shared__ __align__(16) float a1s[128];
  __shared__ __align__(16) float fis[64];
  __shared__ __align__(16) float b1s[128];
  __shared__ __align__(16) float lkrawT[16][64];            // 4 KB  [c=(mt,lg)][row]
  __shared__ __align__(16) f32x2 p01rawT[16][32];           // 4 KB  [c][row<32]
  __shared__ __align__(16) unsigned keybuf[64];
  __shared__ int idxs[32];
  __shared__ int s_u, s_upd, s_utc;
  __shared__ unsigned s_mu, s_mi;

  const int t = threadIdx.x;
  const int lane = t & 63;
  const int wave = t >> 6;
  const int l15 = lane & 15;
  const int lg = lane >> 4;            // 0..3
  const int mt = wave & 3;             // W2-col tile
  const int m0 = mt << 4;
  const int c16 = (mt << 2) + lg;      // raw-partial column id

  unsigned* const uAsh = (unsigned*)Ash;
  unsigned* const uAsm = (unsigned*)Asm;
  unsigned* const uAsl = (unsigned*)Asl;

  // ---- one-time staging: full transposed W1 (coalesced global reads) ----
  for (int idx = t; idx < 16384; idx += 512) {
    int e = idx >> 7, c = idx & 127;     // consecutive lanes -> consecutive c
    W1T[c * 130 + e] = W1[e * 128 + c];
  }
  if (t < 128) b1s[t] = b1[t];
  for (int idx = 33 * 64 + t; idx < 48 * 64; idx += 512) {  // zero pad rows
    uAsh[idx] = 0u; uAsm[idx] = 0u; uAsl[idx] = 0u;
  }
  const float blkv = b_lk[0];
  const float ba0 = b_act[0];
  const float ba1 = b_act[1];
  const float bembr = b_emb[lane];
  // W2^T A-frags split-3 in VGPRs: col = m0+l15, k = 32kc + 8lg + e
  bf16x8 wh[4], wm[4], wl[4];
  #pragma unroll
  for (int kc = 0; kc < 4; ++kc) {
    bf16x8 vh, vm_, vl;
    #pragma unroll
    for (int e = 0; e < 8; ++e) {
      int k = (kc << 5) + (lg << 3) + e;
      float x = W2[k * 64 + m0 + l15];
      unsigned short sh, sm, sl;
      split3(x, sh, sm, sl);
      vh[e] = (short)sh; vm_[e] = (short)sm; vl[e] = (short)sl;
    }
    wh[kc] = vh; wm[kc] = vm_; wl[kc] = vl;
  }
  // hoisted epilogue constants
  const f32x4 c0init = *(const f32x4*)&b2[m0 + (lg << 2)];
  const f32x4 wl4 = *(const f32x4*)&W_lk[m0 + (lg << 2)];
  f32x4 wa0v, wa1v;
  #pragma unroll
  for (int r = 0; r < 4; ++r) {
    f32x2 w2a = *(const f32x2*)&W_act[(m0 + (lg << 2) + r) << 1];
    wa0v[r] = w2a[0]; wa1v[r] = w2a[1];
  }
  // hoisted B1 constants
  int kk[4]; unsigned wb[4]; const float2* ylp[4];
  #pragma unroll
  for (int n = 0; n < 4; ++n) {
    kk[n] = wave + (n << 3);
    wb[n] = (unsigned)((kk[n] << 6) + (lane ^ ((kk[n] & 7) << 2)));
    ylp[n] = (const float2*)&Yl[kk[n]][lane << 1];
  }
  const unsigned wb32 = 2048u + (unsigned)lane;   // row 32, swz=0
  // hoisted B2 read offsets (ushort units)
  const int ntA = (wave < 4) ? 0 : 1;
  const int rowA = (ntA << 4) + l15;
  const int rowB = 32 + l15;                       // only waves 0-3
  int aoA[4], aoB[4];
  #pragma unroll
  for (int kc = 0; kc < 4; ++kc) {
    aoA[kc] = (rowA << 7) + ((((kc << 2) + lg) ^ (rowA & 7)) << 3);
    aoB[kc] = (rowB << 7) + ((((kc << 2) + lg) ^ (rowB & 7)) << 3);
  }
  const float2* const a1p = (const float2*)&a1s[lane << 1];
  // wave-0 register state
  unsigned vm = 0xFFFFFFFFu; float cntf = 0.f; int done = 0;
  int ridx = 0; float gisr = 0.f, sumgr = 0.f;
  // next-node prefetch registers (neighbors / G0 are read-only)
  int vA0 = neighbors[t >> 5];
  int vA1 = neighbors[16 + (t >> 5)];
  int vB  = neighbors[t >> 4];
  int vI  = (t < 32) ? neighbors[t] : 0;
  float gn = (wave == 0) ? G0[lane] : 0.f;

  for (int i = 0; i < 1024; ++i) {
    // ---- full drain once per node: prior node's feature/Y stores must be
    //      visible to this node's phase0 loads ----
    __syncthreads();
    const float gcur = gn;
    // ---- phase0: per-node prefetch into LDS (v-indices already in regs) ----
    {
      const int c4 = (t & 31) << 2;
      *(float4*)&Yl [t >> 5][c4]        = *(const float4*)&Y [vA0 * 128 + c4];
      *(float4*)&Y0l[t >> 5][c4]        = *(const float4*)&Y0[vA0 * 128 + c4];
      *(float4*)&Yl [16 + (t >> 5)][c4] = *(const float4*)&Y [vA1 * 128 + c4];
      *(float4*)&Y0l[16 + (t >> 5)][c4] = *(const float4*)&Y0[vA1 * 128 + c4];
    }
    {
      int k = t >> 4;
      int c4 = (t & 15) << 2;
      *(float4*)&G0l[k][c4] = *(const float4*)&G0[vB * 64 + c4];
    }
    if (t < 64) fis[t] = feature[(i << 6) + t];
    if (t < 32) idxs[t] = vI;
    // issue next node's register prefetch (independent, read-only)
    {
      int j = (i + 1) & 1023;
      const int* __restrict__ nb = neighbors + (j << 5);
      vA0 = nb[t >> 5];
      vA1 = nb[16 + (t >> 5)];
      vB  = nb[t >> 4];
      if (t < 32) vI = nb[t];
      if (wave == 0) gn = G0[(j << 6) + lane];
    }
    bar_lgkm();
    // ---- a1 = fi @ W1a + b1 (W1T b64 reads; chain bit-identical) ----
    if (t < 128) {
      float aa0 = b1s[t], aa1 = 0.0f;
      const float* w1r = &W1T[t * 130];
      #pragma unroll 8
      for (int e = 0; e < 64; e += 2) {
        f32x2 wv = *(const f32x2*)&w1r[e];
        aa0 = fmaf(fis[e],     wv[0], aa0);
        aa1 = fmaf(fis[e + 1], wv[1], aa1);
      }
      a1s[t] = aa0 + aa1;
    }
    int vn[4];
    #pragma unroll
    for (int n = 0; n < 4; ++n) vn[n] = idxs[kk[n]];
    if (wave == 0) {
      ridx = idxs[lane & 31];
      gisr = gcur;
      sumgr = 0.f; vm = 0xFFFFFFFFu; cntf = 0.f; done = 0;
    }
    bar_lgkm();

    for (int st = 0; st < 3; ++st) {
      // ---- B1: 4 rows/wave (+row 32 by wave 4); cvt_pk split-3 ----
      {
        float2 av = *a1p;
        #pragma unroll
        for (int n = 0; n < 4; ++n) {
          float hx = av.x, hy = av.y;
          if (vn[n] > 0) {                         // wave-uniform branch
            float2 yv = *ylp[n];
            hx += yv.x; hy += yv.y;
          }
          hx = fmaxf(hx, 0.f); hy = fmaxf(hy, 0.f);
          unsigned ph, pm, pl;
          split3_pk(hx, hy, ph, pm, pl);
          uAsh[wb[n]] = ph; uAsm[wb[n]] = pm; uAsl[wb[n]] = pl;
        }
        if (wave == 4) {
          float hx = fmaxf(av.x, 0.f), hy = fmaxf(av.y, 0.f);
          unsigned ph, pm, pl;
          split3_pk(hx, hy, ph, pm, pl);
          uAsh[wb32] = ph; uAsm[wb32] = pm; uAsl[wb32] = pl;
        }
      }
      bar_lgkm();
      // ---- B2: MFMA tiles (waves 0-3: rows 0-15 & 32-47; waves 4-7: 16-31) --
      {
        f32x4 cA = c0init, cB = c0init;
        const bool twoT = (wave < 4);
        #pragma unroll
        for (int kc = 0; kc < 4; ++kc) {
          bf16x8 ahA = *(const bf16x8*)&Ash[aoA[kc]];
          bf16x8 amA = *(const bf16x8*)&Asm[aoA[kc]];
          bf16x8 alA = *(const bf16x8*)&Asl[aoA[kc]];
          cA = __builtin_amdgcn_mfma_f32_16x16x32_bf16(wh[kc], ahA, cA, 0, 0, 0);
          cA = __builtin_amdgcn_mfma_f32_16x16x32_bf16(wh[kc], amA, cA, 0, 0, 0);
          cA = __builtin_amdgcn_mfma_f32_16x16x32_bf16(wm[kc], ahA, cA, 0, 0, 0);
          cA = __builtin_amdgcn_mfma_f32_16x16x32_bf16(wh[kc], alA, cA, 0, 0, 0);
          cA = __builtin_amdgcn_mfma_f32_16x16x32_bf16(wl[kc], ahA, cA, 0, 0, 0);
          cA = __builtin_amdgcn_mfma_f32_16x16x32_bf16(wm[kc], amA, cA, 0, 0, 0);
          if (twoT) {
            bf16x8 ahB = *(const bf16x8*)&Ash[aoB[kc]];
            bf16x8 amB = *(const bf16x8*)&Asm[aoB[kc]];
            bf16x8 alB = *(const bf16x8*)&Asl[aoB[kc]];
            cB = __builtin_amdgcn_mfma_f32_16x16x32_bf16(wh[kc], ahB, cB, 0, 0, 0);
            cB = __builtin_amdgcn_mfma_f32_16x16x32_bf16(wh[kc], amB, cB, 0, 0, 0);
            cB = __builtin_amdgcn_mfma_f32_16x16x32_bf16(wm[kc], ahB, cB, 0, 0, 0);
            cB = __builtin_amdgcn_mfma_f32_16x16x32_bf16(wh[kc], alB, cB, 0, 0, 0);
            cB = __builtin_amdgcn_mfma_f32_16x16x32_bf16(wl[kc], ahB, cB, 0, 0, 0);
            cB = __builtin_amdgcn_mfma_f32_16x16x32_bf16(wm[kc], amB, cB, 0, 0, 0);
          }
        }
        // epilogue A: raw per-lg partials (no shfl)
        {
          float pl = 0.f, q0 = 0.f, q1 = 0.f;
          #pragma unroll
          for (int r = 0; r < 4; ++r) {
            float v = fmaxf(cA[r], 0.f);
            pl = fmaf(v, wl4[r], pl);
            q0 = fmaf(v, wa0v[r], q0);
            q1 = fmaf(v, wa1v[r], q1);
          }
          lkrawT[c16][rowA] = pl;
          p01rawT[c16][rowA] = (f32x2){q0, q1};
        }
        if (twoT) {   // row 32 never feeds the action head: lk partial only
          float pl = 0.f;
          #pragma unroll
          for (int r = 0; r < 4; ++r) {
            float v = fmaxf(cB[r], 0.f);
            pl = fmaf(v, wl4[r], pl);
          }
          lkrawT[c16][rowB] = pl;
        }
      }
      bar_lgkm();
      // ---- P4+D (wave 0): assemble lk (bit-identical nesting), LDS-key
      //      argmax, action head, state update ----
      if (wave == 0) {
        float v_[16];
        #pragma unroll
        for (int c = 0; c < 16; ++c) v_[c] = lkrawT[c][lane];
        float s0 = (v_[0] + v_[1]) + (v_[2] + v_[3]);
        float s1 = (v_[4] + v_[5]) + (v_[6] + v_[7]);
        float s2 = (v_[8] + v_[9]) + (v_[10] + v_[11]);
        float s3 = (v_[12] + v_[13]) + (v_[14] + v_[15]);
        float lkv = ((s0 + s1) + (s2 + s3)) + blkv;
        unsigned b = __builtin_bit_cast(unsigned, lkv);
        int sb = (int)b >> 31;
        unsigned mono = b ^ (0x80000000u | (unsigned)sb);
        bool valid = (lane == 32) || ((lane < 32) && ((vm >> lane) & 1u));
        unsigned key = valid ? mono : 0u;
        keybuf[lane] = key;
        asm volatile("s_waitcnt lgkmcnt(0)" ::: "memory");
        __builtin_amdgcn_sched_barrier(0);
        const uint4* kb = (const uint4*)keybuf;
        unsigned mx = 0u;
        #pragma unroll
        for (int c = 0; c < 16; ++c) {
          uint4 kv = kb[c];
          unsigned m01 = kv.x > kv.y ? kv.x : kv.y;
          unsigned m23 = kv.z > kv.w ? kv.z : kv.w;
          unsigned mm = m01 > m23 ? m01 : m23;
          mx = mx > mm ? mx : mm;
        }
        unsigned long long am = __ballot(valid && (key == mx));
        const int ut = (int)(__ffsll(am) - 1);
        const int utc = ut < 31 ? ut : 31;
        f32x2 q[16];
        #pragma unroll
        for (int c = 0; c < 16; ++c) q[c] = p01rawT[c][utc];
        f32x2 S0 = (q[0] + q[1]) + (q[2] + q[3]);
        f32x2 S1 = (q[4] + q[5]) + (q[6] + q[7]);
        f32x2 S2 = (q[8] + q[9]) + (q[10] + q[11]);
        f32x2 S3 = (q[12] + q[13]) + (q[14] + q[15]);
        f32x2 D01 = (S0 + S1) + (S2 + S3);
        float d0 = D01[0] + ba0;
        float d1 = D01[1] + ba1;
        const int at1 = (d1 > d0) ? 1 : 0;
        const int newdone = done | (ut == 32);
        const int upd = newdone ? 0 : 1;
        done = newdone;
        const float take = at1 ? 1.0f : 0.0f;
        const float denom = cntf + take + 1.0f;
        const int u = __builtin_amdgcn_readlane(ridx, utc);
        unsigned long long bu = __ballot(lane < 32 && ridx == u);
        unsigned long long bi = __ballot(lane < 32 && ridx == i);
        if (lane == 0) {
          s_u = u; s_upd = upd; s_utc = utc;
          s_mu = (unsigned)bu; s_mi = (unsigned)bi;
        }
        if (upd) {
          vm &= ~(1u << utc);
          cntf += take;
          const float gu = G0l[utc][lane];
          const float ns = sumgr + take * gu;
          const float hv = (ns + gisr) / denom;
          const float nfi = fmaxf(hv + bembr, 0.0f);
          sumgr = ns;
          const float f0u = fmaxf(gu + bembr, 0.0f);   // == feat0[u] bit-exact
          feature[(i << 6) + lane] = nfi;              // feature[u] wins if u==i
          feature[(u << 6) + lane] = f0u;
          fis[lane] = (u == i) ? f0u : nfi;
        }
      }
      bar_lgkm();
      if (!s_upd) break;
      // ---- E: waves 0-1 -> Y rows + Yl patches; waves 2-3 -> a1 ----
      if (wave < 4) {
        const int u = s_u;
        const int c = t & 127;
        const float* w1r = &W1T[c * 130];
        if (wave < 2) {
          const float yu = Y0l[s_utc][c];              // LDS (was global Y0[u])
          f32x2 acc = {0.f, 0.f};
          #pragma unroll 8
          for (int e = 0; e < 64; e += 2) {
            f32x2 fv = *(const f32x2*)&fis[e];
            f32x2 wv = *(const f32x2*)&w1r[64 + e];
            acc = __builtin_elementwise_fma(fv, wv, acc);
          }
          const float yi = acc[0] + acc[1];
          Y[i * 128 + c] = yi;                         // Y[u] wins if u==i
          Y[u * 128 + c] = yu;
          const unsigned mu = s_mu;
          for (unsigned m = mu; m; m &= m - 1) {
            int k = __ffs(m) - 1;
            Yl[k][c] = yu;
          }
          for (unsigned m = s_mi & ~mu; m; m &= m - 1) {
            int k = __ffs(m) - 1;
            Yl[k][c] = yi;
          }
        } else {
          f32x2 aa = {b1s[c], 0.f};
          #pragma unroll 8
          for (int e = 0; e < 64; e += 2) {
            f32x2 fv = *(const f32x2*)&fis[e];
            f32x2 wv = *(const f32x2*)&w1r[e];
            aa = __builtin_elementwise_fma(fv, wv, aa);
          }
          a1s[c] = aa[0] + aa[1];
        }
      }
      bar_lgkm();
    }
  }
}

// ---------------------------------------------------------------------------
extern "C" void kernel_launch(void* const* d_in, const int* in_sizes, int n_in,
                              void* d_out, int out_size, void* d_ws, size_t ws_size,
                              hipStream_t stream) {
  const float* X     = (const float*)d_in[0];
  const int*   nbr   = (const int*)  d_in[1];
  const float* W_emb = (const float*)d_in[2];
  const float* b_emb = (const float*)d_in[3];
  const float* W1    = (const float*)d_in[4];
  const float* b1    = (const float*)d_in[5];
  const float* W2    = (const float*)d_in[6];
  const float* b2    = (const float*)d_in[7];
  const float* W_lk  = (const float*)d_in[8];
  const float* b_lk  = (const float*)d_in[9];
  const float* W_act = (const float*)d_in[10];
  const float* b_act = (const float*)d_in[11];
  float* out = (float*)d_out;
  float* ws  = (float*)d_ws;
  float* G0    = ws;             // [1024*64]
  float* feat0 = ws + 65536;     // [1024*64]
  float* Y0    = ws + 131072;    // [1024*128]
  float* Y     = ws + 262144;    // [1024*128]

  hipLaunchKernelGGL(k_embed, dim3(256), dim3(256), 0, stream,
                     X, W_emb, b_emb, G0, feat0, out);
  hipLaunchKernelGGL(k_y0, dim3(1024), dim3(128), 0, stream,
                     feat0, W1, Y0, Y);
  hipLaunchKernelGGL(k_serial, dim3(1), dim3(512), 0, stream,
                     nbr, W1, b1, W2, b2, W_lk, b_lk, W_act, b_act, b_emb,
                     G0, feat0, Y0, Y, out);
}